// Round 5
// baseline (253.545 us; speedup 1.0000x reference)
//
#include <hip/hip_runtime.h>

// VQ: z [16384,512] f32, emb [8192,512] f32
// outputs (flat f32): z_q [8388608], loss [1], idx [16384], var [1]

#define BT   16384
#define DIMS 512
#define NE   8192
#define NS   4                       // n-splits
#define BN   256
#define NTPB (NE / NS / BN)          // n-tiles per block = 8
#define NSTEPS 64                    // NTPB * DIMS/64 flat K-steps

// out layout (float elements)
#define LOSS_OFF 8388608
#define IDX_OFF  8388609
#define V_OFF    8404993

// ws layout (bytes)
#define BEST_OFF  0         // u64[16384]
#define ENORM_OFF 131072    // f32[8192]
#define SUMS_OFF  163840    // double[3]
#define CNT_OFF   163864    // unsigned

typedef __attribute__((ext_vector_type(8))) short short8;
typedef __attribute__((ext_vector_type(4))) float floatx4;

#define AS1(p) ((const __attribute__((address_space(1))) void*)(p))
#define AS3(p) ((__attribute__((address_space(3))) void*)(p))

__device__ __forceinline__ unsigned f2bf(float f) {
    unsigned u = __builtin_bit_cast(unsigned, f);
    u += 0x7FFFu + ((u >> 16) & 1u);          // RNE
    return u >> 16;
}

// fused prep: emb->bf16 + ||e||^2 (blocks 0..NE/4), z->bf16 (rest), init best/sums/counter
__global__ __launch_bounds__(256) void prep_kernel(
    const float* __restrict__ z, const float* __restrict__ emb,
    ushort* __restrict__ zh, ushort* __restrict__ ehh,
    float* __restrict__ enorm, unsigned long long* __restrict__ best,
    double* __restrict__ sums, unsigned* __restrict__ counter)
{
    const int lane = threadIdx.x & 63, w = threadIdx.x >> 6;
    const int b = blockIdx.x;
    if (b < NE / 4) {
        const int row = b * 4 + w;
        const float4* p = (const float4*)(emb + (size_t)row * DIMS + lane * 8);
        float4 a = p[0], bb = p[1];
        uint4 h;
        h.x = f2bf(a.x) | (f2bf(a.y) << 16);
        h.y = f2bf(a.z) | (f2bf(a.w) << 16);
        h.z = f2bf(bb.x) | (f2bf(bb.y) << 16);
        h.w = f2bf(bb.z) | (f2bf(bb.w) << 16);
        *(uint4*)(ehh + (size_t)row * DIMS + lane * 8) = h;
        float s = a.x*a.x + a.y*a.y + a.z*a.z + a.w*a.w
                + bb.x*bb.x + bb.y*bb.y + bb.z*bb.z + bb.w*bb.w;
        #pragma unroll
        for (int off = 32; off > 0; off >>= 1) s += __shfl_down(s, off, 64);
        if (lane == 0) enorm[row] = s;
    } else {
        const int row = (b - NE / 4) * 4 + w;
        const float4* p = (const float4*)(z + (size_t)row * DIMS + lane * 8);
        float4 a = p[0], bb = p[1];
        uint4 h;
        h.x = f2bf(a.x) | (f2bf(a.y) << 16);
        h.y = f2bf(a.z) | (f2bf(a.w) << 16);
        h.z = f2bf(bb.x) | (f2bf(bb.y) << 16);
        h.w = f2bf(bb.z) | (f2bf(bb.w) << 16);
        *(uint4*)(zh + (size_t)row * DIMS + lane * 8) = h;
    }
    const int gid = b * 256 + threadIdx.x;
    if (gid < BT) best[gid] = 0xFFFFFFFFFFFFFFFFULL;
    if (gid == 0) { sums[0] = 0.0; sums[1] = 0.0; sums[2] = 0.0; *counter = 0u; }
}

// 256x256-tile 8-wave argmin GEMM — single barrier/step AND counted vmcnt.
// R3 (2 barriers, vmcnt(4), 2-ahead A) = 129.5us; R4 (1 barrier, vmcnt(0),
// 1-ahead) = 137us -> the counted vmcnt mattered more than the barrier.
// This round combines them via TRIPLE-buffered A: A(s+2) targets buffer
// (s+2)%3, which no wave reads during step s (barrier bounds skew to one
// step; all step-s reads are LGK(0)-retired before any wave passes the
// boundary barrier, so a fast wave restaging buffer s%3 in step s+1 is
// safe).  Boundary: per-wave issue order [B(s+1) @p0, A(s+2) @p1],
// s_waitcnt vmcnt(4) -> B(s+1)/A(s+1) proven landed, A(s+2) rides across.
// LDS = 3x32K A + 2x32K B = 160 KiB exactly; enorm evicted from LDS and
// read per-fold (once per 8 steps) via asm global_load_dword + vmcnt(0)
// (older in-flight staging loads are ~2500cy old by then -> drain costs
// only the enorm L2 hit).  A-read/stage bases rotate through 3 registers.
// Frag regs a[4][2]+b[4] = 48 VGPR (unchanged).  Per-acc MFMA order
// unchanged (k0 asc, kk0 then kk1) -> bitwise-identical scores, tie-break,
// absmax vs previous rounds.

#define DSR8(dst, IDX) do {                                                    \
    unsigned addr_ = (unsigned)(size_t)AS3(&lds[IDX]);                         \
    asm volatile("ds_read_b128 %0, %1" : "=v"(dst) : "v"(addr_));              \
} while (0)

#define LGK(N_) do {                                                           \
    asm volatile("s_waitcnt lgkmcnt(" #N_ ")" ::: "memory");                   \
    __builtin_amdgcn_sched_barrier(0);                                         \
} while (0)

#define CL4(J_, BIDX_, KK_)                                                    \
    _Pragma("unroll")                                                          \
    for (int mi = 0; mi < 4; mi++)                                             \
        acc[mi][J_] = __builtin_amdgcn_mfma_f32_16x16x32_bf16(                 \
            a[mi][KK_], b[BIDX_], acc[mi][J_], 0, 0, 0);

// staging: source addr clamped (tail steps re-load valid data into buffers
// that are never read again — branchless)
#define STAGE_A(SA_, H_, DST_) do {                                            \
    const int sc_ = (SA_) & 63;                                                \
    const unsigned al_ = (DST_) + (unsigned)((((H_) * 128) + w * 8) * 64);     \
    const ushort* g_ = zA + (size_t)((H_) * 128) * DIMS + soff                 \
                     + ((sc_ & 7) * 64);                                       \
    __builtin_amdgcn_global_load_lds(AS1(g_), AS3(&lds[al_]), 16, 0, 0);       \
    __builtin_amdgcn_global_load_lds(AS1(g_ + (size_t)64 * DIMS),              \
                                     AS3(&lds[al_ + 4096]), 16, 0, 0);         \
} while (0)

#define STAGE_B(SB_, H_, DST_) do {                                            \
    const int sc_ = (SB_) & 63;                                                \
    const unsigned bl_ = (DST_) + (unsigned)((((H_) * 128) + w * 8) * 64);     \
    const ushort* g_ = eh + (size_t)(nsN + (sc_ >> 3) * 256 + (H_) * 128) * DIMS \
                     + soff + ((sc_ & 7) * 64);                                \
    __builtin_amdgcn_global_load_lds(AS1(g_), AS3(&lds[bl_]), 16, 0, 0);       \
    __builtin_amdgcn_global_load_lds(AS1(g_ + (size_t)64 * DIMS),              \
                                     AS3(&lds[bl_ + 4096]), 16, 0, 0);         \
} while (0)

// Per-step DS-queue schedule (in-order completion, per wave):
//   p0 issues r1-8  = A kk0, B0-3 kk0;  stage B(s+1) h0+h1 (opp B buf);
//       clusters J0-3 kk0 wait 3/2/1/0
//   p1 issues r9-16 = B4-7 kk0, A kk1;  stage A(s+2) h0+h1 (buf (s+2)%3);
//       clusters J4-7 kk0 wait 7/6/5/4
//   p2 issues r17-20 = B0-3 kk1;  clusters J0-3 kk1 wait 3/2/1/0
//   p3 issues r21-24 = B4-7 kk1;  clusters J4-7 kk1 wait 3/2/1/0
//   vmcnt(4) [A(s+2) rides across]; ONE s_barrier.
// TM_: 0 -> vmcnt(4) boundary wait, 2 -> none (last step; epilogue drains)
#define STEP(S_, AR_, BR_, AW_, BW_, TM_) do {                                 \
    const int s_ = (S_);                                                       \
    short8 a[4][2], b[4];                                                      \
    /* p0 */                                                                   \
    _Pragma("unroll") for (int mi = 0; mi < 4; mi++)                           \
        DSR8(a[mi][0], (AR_) + aro + mi * 1024 + pxo0);                        \
    _Pragma("unroll") for (int j = 0; j < 4; j++)                              \
        DSR8(b[j], (BR_) + bro + j * 1024 + pxo0);                             \
    STAGE_B(s_ + 1, 0, BW_); STAGE_B(s_ + 1, 1, BW_);                          \
    __builtin_amdgcn_s_setprio(1);                                             \
    LGK(3); CL4(0, 0, 0); LGK(2); CL4(1, 1, 0);                                \
    LGK(1); CL4(2, 2, 0); LGK(0); CL4(3, 3, 0);                                \
    __builtin_amdgcn_s_setprio(0);                                             \
    /* p1 */                                                                   \
    _Pragma("unroll") for (int j = 0; j < 4; j++)                              \
        DSR8(b[j], (BR_) + bro + (4 + j) * 1024 + pxo0);                       \
    _Pragma("unroll") for (int mi = 0; mi < 4; mi++)                           \
        DSR8(a[mi][1], (AR_) + aro + mi * 1024 + pxo1);                        \
    STAGE_A(s_ + 2, 0, AW_); STAGE_A(s_ + 2, 1, AW_);                          \
    __builtin_amdgcn_s_setprio(1);                                             \
    LGK(7); CL4(4, 0, 0); LGK(6); CL4(5, 1, 0);                                \
    LGK(5); CL4(6, 2, 0); LGK(4); CL4(7, 3, 0);                                \
    __builtin_amdgcn_s_setprio(0);                                             \
    /* p2 */                                                                   \
    _Pragma("unroll") for (int j = 0; j < 4; j++)                              \
        DSR8(b[j], (BR_) + bro + j * 1024 + pxo1);                             \
    __builtin_amdgcn_s_setprio(1);                                             \
    LGK(3); CL4(0, 0, 1); LGK(2); CL4(1, 1, 1);                                \
    LGK(1); CL4(2, 2, 1); LGK(0); CL4(3, 3, 1);                                \
    __builtin_amdgcn_s_setprio(0);                                             \
    /* p3 */                                                                   \
    _Pragma("unroll") for (int j = 0; j < 4; j++)                              \
        DSR8(b[j], (BR_) + bro + (4 + j) * 1024 + pxo1);                       \
    __builtin_amdgcn_s_setprio(1);                                             \
    LGK(3); CL4(4, 0, 1); LGK(2); CL4(5, 1, 1);                                \
    LGK(1); CL4(6, 2, 1); LGK(0); CL4(7, 3, 1);                                \
    __builtin_amdgcn_s_setprio(0);                                             \
    __builtin_amdgcn_sched_barrier(0);                                         \
    if ((TM_) == 0) asm volatile("s_waitcnt vmcnt(4)" ::: "memory");           \
    __builtin_amdgcn_s_barrier();                                              \
} while (0)

__global__ __launch_bounds__(512, 2) void argmin_mfma(
    const ushort* __restrict__ zh, const ushort* __restrict__ eh,
    const float* __restrict__ enorm, unsigned long long* __restrict__ best)
{
    // ushort-indexed: A bufs x3 @ 0 / 16384 / 32768 (each 256 rows x 64),
    // B bufs x2 @ 49152 / 65536.  Total 81920 ushorts = 160 KiB exactly.
    __shared__ __align__(16) ushort lds[81920];

    const int t = threadIdx.x;
    const int w = t >> 6, lane = t & 63;
    const int quad = lane >> 4, l15 = lane & 15;

    // XCD-pairing swizzle (bijective, 256 blocks): each XCD's 32 resident
    // blocks share one 2MB B-panel in its L2.
    const int d = blockIdx.x;
    const int xcd = d & 7, slot = d >> 3;
    const int ns = xcd >> 1;
    const int mt = slot * 2 + (xcd & 1);
    const int m0 = mt * 256;
    const int nsN = ns * (NTPB * BN);         // 2048 * ns

    const int wrow = (w & 3) * 64;            // wave row base in A tile
    const int wcol = (w >> 2) * 128;          // wave col base in B tile

    // staging lane geometry (pre-swizzled global source, linear LDS dest)
    const int l8 = lane >> 3, c8 = lane & 7;
    const int chunk = c8 ^ l8;
    const int soff = (w * 8 + l8) * DIMS + chunk * 8;
    const ushort* zA = zh + (size_t)m0 * DIMS;
    const float* enormg = enorm + nsN;

    // frag-read physical chunk offsets (ushorts): (kk*4+quad)^(l15&7) * 8
    const int pxo0 = (quad ^ (l15 & 7)) * 8;
    const int pxo1 = ((4 + quad) ^ (l15 & 7)) * 8;
    const int aro = (wrow + l15) * 64;
    const int bro = (wcol + l15) * 64;

    floatx4 acc[4][8];
    #pragma unroll
    for (int mi = 0; mi < 4; mi++)
        #pragma unroll
        for (int nj = 0; nj < 8; nj++)
            acc[mi][nj] = (floatx4){0.f, 0.f, 0.f, 0.f};

    float bs[16];
    int   bn_[16];
    #pragma unroll
    for (int k = 0; k < 16; k++) { bs[k] = 3.4e38f; bn_[k] = 0; }

    // prologue: A(0)->buf0, B(0)->B0, A(1)->buf1; vmcnt(4) -> A(0)/B(0)
    // landed, A(1) rides; barrier
    STAGE_A(0, 0, 0u);     STAGE_A(0, 1, 0u);
    STAGE_B(0, 0, 49152u); STAGE_B(0, 1, 49152u);
    STAGE_A(1, 0, 16384u); STAGE_A(1, 1, 16384u);
    asm volatile("s_waitcnt vmcnt(4)" ::: "memory");
    __builtin_amdgcn_s_barrier();

    // A-buffer base rotation: step s reads aR (= buf s%3), stages A(s+2)
    // into aW (= buf (s+2)%3); rotate (aR,aN,aW) <- (aN,aW,aR) each step.
    unsigned aR = 0u, aN = 16384u, aW = 32768u;

    for (int sp = 0; sp < NSTEPS; sp += 2) {
        STEP(sp, aR, 49152u, aW, 65536u, 0);
        { unsigned t_ = aR; aR = aN; aN = aW; aW = t_; }
        STEP(sp + 1, aR, 65536u, aW, 49152u, (sp == NSTEPS - 2) ? 2 : 0);
        { unsigned t_ = aR; aR = aN; aN = aW; aW = t_; }

        if ((sp & 7) == 6) {
            // n-tile finished: fold scores into running best, reset acc.
            // C/D frag: col = l15 (n), row = quad*4 + r (m).
            // enorm via global (L2-hot); vmcnt(0) also retires staging loads
            // that are ~2500cy old by now -> drain cost ~= enorm L2 latency.
            const int nt = sp >> 3;
            const int eb = nt * 256 + wcol + l15;
            const int nbase = nsN + eb;
            float en[8];
            #pragma unroll
            for (int nj = 0; nj < 8; nj++) {
                const float* ep_ = enormg + eb + nj * 16;
                asm volatile("global_load_dword %0, %1, off"
                             : "=v"(en[nj]) : "v"(ep_));
            }
            asm volatile("s_waitcnt vmcnt(0)" ::: "memory");
            __builtin_amdgcn_sched_barrier(0);
            #pragma unroll
            for (int nj = 0; nj < 8; nj++) {          // nj asc = n asc
                const int n = nbase + nj * 16;
                #pragma unroll
                for (int mi = 0; mi < 4; mi++) {
                    #pragma unroll
                    for (int r = 0; r < 4; r++) {
                        const int k = mi * 4 + r;
                        const float sc = fmaf(-2.0f, acc[mi][nj][r], en[nj]);
                        if (sc < bs[k]) { bs[k] = sc; bn_[k] = n; }
                    }
                    acc[mi][nj] = (floatx4){0.f, 0.f, 0.f, 0.f};
                }
            }
        }
    }

    // drain tail staging gloads before epilogue/endpgm (once, cheap)
    asm volatile("s_waitcnt vmcnt(0)" ::: "memory");

    // once per block: pack, shfl-min over l15 group, atomicMin across splits
    #pragma unroll
    for (int mi = 0; mi < 4; mi++)
        #pragma unroll
        for (int r = 0; r < 4; r++) {
            const int k = mi * 4 + r;
            unsigned su = __builtin_bit_cast(unsigned, bs[k]);
            su = (su & 0x80000000u) ? ~su : (su | 0x80000000u);  // order-preserving
            unsigned long long key = ((unsigned long long)su << 32) | (unsigned)bn_[k];
            #pragma unroll
            for (int off = 1; off < 16; off <<= 1) {
                unsigned long long o = __shfl_xor(key, off, 64);
                key = (o < key) ? o : key;
            }
            if (l15 == 0) atomicMin(&best[m0 + wrow + mi * 16 + quad * 4 + r], key);
        }
}

// one block per 32 rows: idx from packed keys, gather z_q, loss + idx stats;
// last block to finish runs the finalize.
__global__ __launch_bounds__(256) void gather_loss_kernel(
    const float* __restrict__ z, const float* __restrict__ emb,
    const unsigned long long* __restrict__ best,
    float* __restrict__ out, double* __restrict__ sums, unsigned* __restrict__ counter)
{
    __shared__ int sIdx[32];
    __shared__ double red[4];
    const int t = threadIdx.x;
    const int row0 = blockIdx.x * 32;
    double myIdxSum = 0.0, myIdxSq = 0.0;
    if (t < 32) {
        int row = row0 + t;
        int idx = (int)(unsigned)(best[row] & 0xFFFFFFFFULL);
        sIdx[t] = idx;
        out[IDX_OFF + row] = (float)idx;
        myIdxSum = (double)idx;
        myIdxSq = (double)idx * (double)idx;
    }
    __syncthreads();
    double acc = 0.0;
    #pragma unroll 4
    for (int i = 0; i < 16; i++) {
        int e = i * 1024 + t * 4;        // 32 rows x 512 = 16384 elems per block
        int rl = e >> 9;
        int c = e & 511;
        int idx = sIdx[rl];
        float4 zv = *(const float4*)(z + (size_t)(row0 + rl) * DIMS + c);
        float4 ev = *(const float4*)(emb + (size_t)idx * DIMS + c);
        *(float4*)(out + (size_t)(row0 + rl) * DIMS + c) = ev;  // z_q_st value == z_q
        float dx = zv.x - ev.x, dy = zv.y - ev.y;
        float dz = zv.z - ev.z, dw = zv.w - ev.w;
        acc += (double)(dx * dx + dy * dy) + (double)(dz * dz + dw * dw);
    }
    const int lane = t & 63, wv = t >> 6;
    #pragma unroll
    for (int off = 32; off > 0; off >>= 1) {
        acc      += __shfl_down(acc, off, 64);
        myIdxSum += __shfl_down(myIdxSum, off, 64);
        myIdxSq  += __shfl_down(myIdxSq, off, 64);
    }
    if (lane == 0) red[wv] = acc;
    __syncthreads();
    if (t == 0) {
        double tot = red[0] + red[1] + red[2] + red[3];
        atomicAdd(&sums[0], tot);
        atomicAdd(&sums[1], myIdxSum);   // wave 0 held all idx stats
        atomicAdd(&sums[2], myIdxSq);
        __threadfence();
        unsigned old = atomicAdd(counter, 1u);
        if (old == gridDim.x - 1) {
            __threadfence();
            double s0 = atomicAdd(&sums[0], 0.0);
            double s1 = atomicAdd(&sums[1], 0.0);
            double s2 = atomicAdd(&sums[2], 0.0);
            out[LOSS_OFF] = (float)(1.25 * s0 / (double)((size_t)BT * DIMS));
            double m = s1 / (double)BT;
            out[V_OFF] = (float)(s2 / (double)BT - m * m);
        }
    }
}

extern "C" void kernel_launch(void* const* d_in, const int* in_sizes, int n_in,
                              void* d_out, int out_size, void* d_ws, size_t ws_size,
                              hipStream_t stream) {
    const float* z = (const float*)d_in[0];
    const float* emb = (const float*)d_in[1];
    float* out = (float*)d_out;
    char* ws = (char*)d_ws;
    unsigned long long* best = (unsigned long long*)(ws + BEST_OFF);
    float* enorm  = (float*)(ws + ENORM_OFF);
    double* sums  = (double*)(ws + SUMS_OFF);
    unsigned* counter = (unsigned*)(ws + CNT_OFF);

    // bf16 scratch in the z_q region of out (fully overwritten by gather at the end)
    ushort* zh = (ushort*)out;
    ushort* ehh = zh + (size_t)BT * DIMS;

    hipLaunchKernelGGL(prep_kernel, dim3(NE / 4 + BT / 4), dim3(256), 0, stream,
                       z, emb, zh, ehh, enorm, best, sums, counter);
    hipLaunchKernelGGL(argmin_mfma, dim3(256), dim3(512), 0, stream,
                       zh, ehh, enorm, best);
    hipLaunchKernelGGL(gather_loss_kernel, dim3(BT / 32), dim3(256), 0, stream,
                       z, emb, best, out, sums, counter);
}

// Round 6
// 248.231 us; speedup vs baseline: 1.0214x; 1.0214x over previous
//
#include <hip/hip_runtime.h>

// VQ: z [16384,512] f32, emb [8192,512] f32
// outputs (flat f32): z_q [8388608], loss [1], idx [16384], var [1]

#define BT   16384
#define DIMS 512
#define NE   8192
#define NS   4                       // n-splits
#define BN   256
#define NTPB (NE / NS / BN)          // n-tiles per block = 8
#define NSTEPS 64                    // NTPB * DIMS/64 flat K-steps

// out layout (float elements)
#define LOSS_OFF 8388608
#define IDX_OFF  8388609
#define V_OFF    8404993

// ws layout (bytes)
#define BEST_OFF  0         // u64[16384]
#define ENORM_OFF 131072    // f32[8192]
#define SUMS_OFF  163840    // double[3]
#define CNT_OFF   163864    // unsigned

typedef __attribute__((ext_vector_type(8))) short short8;
typedef __attribute__((ext_vector_type(4))) float floatx4;

#define AS1(p) ((const __attribute__((address_space(1))) void*)(p))
#define AS3(p) ((__attribute__((address_space(3))) void*)(p))

__device__ __forceinline__ unsigned f2bf(float f) {
    unsigned u = __builtin_bit_cast(unsigned, f);
    u += 0x7FFFu + ((u >> 16) & 1u);          // RNE
    return u >> 16;
}

// fused prep: emb->bf16 + ||e||^2 (blocks 0..NE/4), z->bf16 (rest), init best/sums/counter
__global__ __launch_bounds__(256) void prep_kernel(
    const float* __restrict__ z, const float* __restrict__ emb,
    ushort* __restrict__ zh, ushort* __restrict__ ehh,
    float* __restrict__ enorm, unsigned long long* __restrict__ best,
    double* __restrict__ sums, unsigned* __restrict__ counter)
{
    const int lane = threadIdx.x & 63, w = threadIdx.x >> 6;
    const int b = blockIdx.x;
    if (b < NE / 4) {
        const int row = b * 4 + w;
        const float4* p = (const float4*)(emb + (size_t)row * DIMS + lane * 8);
        float4 a = p[0], bb = p[1];
        uint4 h;
        h.x = f2bf(a.x) | (f2bf(a.y) << 16);
        h.y = f2bf(a.z) | (f2bf(a.w) << 16);
        h.z = f2bf(bb.x) | (f2bf(bb.y) << 16);
        h.w = f2bf(bb.z) | (f2bf(bb.w) << 16);
        *(uint4*)(ehh + (size_t)row * DIMS + lane * 8) = h;
        float s = a.x*a.x + a.y*a.y + a.z*a.z + a.w*a.w
                + bb.x*bb.x + bb.y*bb.y + bb.z*bb.z + bb.w*bb.w;
        #pragma unroll
        for (int off = 32; off > 0; off >>= 1) s += __shfl_down(s, off, 64);
        if (lane == 0) enorm[row] = s;
    } else {
        const int row = (b - NE / 4) * 4 + w;
        const float4* p = (const float4*)(z + (size_t)row * DIMS + lane * 8);
        float4 a = p[0], bb = p[1];
        uint4 h;
        h.x = f2bf(a.x) | (f2bf(a.y) << 16);
        h.y = f2bf(a.z) | (f2bf(a.w) << 16);
        h.z = f2bf(bb.x) | (f2bf(bb.y) << 16);
        h.w = f2bf(bb.z) | (f2bf(bb.w) << 16);
        *(uint4*)(zh + (size_t)row * DIMS + lane * 8) = h;
    }
    const int gid = b * 256 + threadIdx.x;
    if (gid < BT) best[gid] = 0xFFFFFFFFFFFFFFFFULL;
    if (gid == 0) { sums[0] = 0.0; sums[1] = 0.0; sums[2] = 0.0; *counter = 0u; }
}

// 256x256-tile 8-wave argmin GEMM — per-cluster software-pipelined DS reads.
// CHANGE vs R5: R5's phase structure (8-read burst -> LGK-gated MFMA burst)
// serialized the DS unit against the matrix pipe (step 4642cy ~= DS 2800 +
// MFMA 2483; all 8 waves burst reads simultaneously after each barrier, so
// cross-wave skew cannot create overlap).  Now each step is 16 x
// {lgkmcnt(N) -> 4 MFMA -> issue 1 replacement ds_read}: the wave keeps
// 4-8 reads outstanding CONTINUOUSLY, so DS services reads while the
// matrix pipe drains, independent of wave skew.  b[4] regs recycle with a
// sched_barrier(0) pin between each cluster and the read overwriting its
// operand (WAR order -> allocator reuses the same VGPRs; stays at the
// 128 VGPR + 128 AGPR = 256/wave occupancy cliff).  Read schedule
// (in-order DS completion, per wave): r1-4 a.kk0, r5-8 B0-3.kk0,
// r9-12 a.kk1 up front; then waits 7,7,7,7, 3x9, 2,1,0 with one issue
// after each of the first 12 clusters.  Cluster order, per-acc accumulate
// order (k0 asc, kk0 then kk1), staging order, vmcnt(4) boundary, fold,
// tie-break: unchanged -> bitwise-identical scores / absmax.

#define PIN __builtin_amdgcn_sched_barrier(0)
#define P1  __builtin_amdgcn_s_setprio(1)
#define P0  __builtin_amdgcn_s_setprio(0)

#define DSR8O(dst, BASE, OFF) \
    asm volatile("ds_read_b128 %0, %1 offset:" #OFF : "=v"(dst) : "v"(BASE))

#define LGK(N_) do {                                                           \
    asm volatile("s_waitcnt lgkmcnt(" #N_ ")" ::: "memory");                   \
    __builtin_amdgcn_sched_barrier(0);                                         \
} while (0)

#define CL4(J_, BIDX_, KK_)                                                    \
    _Pragma("unroll")                                                          \
    for (int mi = 0; mi < 4; mi++)                                             \
        acc[mi][J_] = __builtin_amdgcn_mfma_f32_16x16x32_bf16(                 \
            a[mi][KK_], b[BIDX_], acc[mi][J_], 0, 0, 0);

// staging: source addr clamped (tail steps re-load valid data into buffers
// that are never read again — branchless)
#define STAGE_A(SA_, H_, DST_) do {                                            \
    const int sc_ = (SA_) & 63;                                                \
    const unsigned al_ = (DST_) + (unsigned)((((H_) * 128) + w * 8) * 64);     \
    const ushort* g_ = zA + (size_t)((H_) * 128) * DIMS + soff                 \
                     + ((sc_ & 7) * 64);                                       \
    __builtin_amdgcn_global_load_lds(AS1(g_), AS3(&lds[al_]), 16, 0, 0);       \
    __builtin_amdgcn_global_load_lds(AS1(g_ + (size_t)64 * DIMS),              \
                                     AS3(&lds[al_ + 4096]), 16, 0, 0);         \
} while (0)

#define STAGE_B(SB_, H_, DST_) do {                                            \
    const int sc_ = (SB_) & 63;                                                \
    const unsigned bl_ = (DST_) + (unsigned)((((H_) * 128) + w * 8) * 64);     \
    const ushort* g_ = eh + (size_t)(nsN + (sc_ >> 3) * 256 + (H_) * 128) * DIMS \
                     + soff + ((sc_ & 7) * 64);                                \
    __builtin_amdgcn_global_load_lds(AS1(g_), AS3(&lds[bl_]), 16, 0, 0);       \
    __builtin_amdgcn_global_load_lds(AS1(g_ + (size_t)64 * DIMS),              \
                                     AS3(&lds[bl_ + 4096]), 16, 0, 0);         \
} while (0)

// Outstanding-count audit (DS in-order per wave):
//  after r1-r12 issued: 12.  C0 needs r1-5 -> LGK(7).  Each of C0-C3
//  issues +1 read (r13-16) and needs r6/r7/r8 -> LGK(7) each.
//  C4 needs r13 -> LGK(3) (also retires a.kk1 r9-12).  C5-C11 each
//  need the read issued 4 clusters earlier -> LGK(3).  C12-C15 drain
//  3/2/1/0.  Max outstanding 12, steady 4-8.
// TM_: 0 -> vmcnt(4) boundary wait, 2 -> none (last step; epilogue drains)
#define STEP(S_, AR_, BR_, AW_, BW_, TM_) do {                                 \
    const int s_ = (S_);                                                       \
    short8 a[4][2], b[4];                                                      \
    const unsigned aV0 = ldsb + 2u * ((AR_) + aro + pxo0);                     \
    const unsigned aV1 = ldsb + 2u * ((AR_) + aro + pxo1);                     \
    const unsigned bV0 = ldsb + 2u * ((BR_) + bro + pxo0);                     \
    const unsigned bV1 = ldsb + 2u * ((BR_) + bro + pxo1);                     \
    DSR8O(a[0][0], aV0, 0);    DSR8O(a[1][0], aV0, 2048);                      \
    DSR8O(a[2][0], aV0, 4096); DSR8O(a[3][0], aV0, 6144);                      \
    DSR8O(b[0], bV0, 0);       DSR8O(b[1], bV0, 2048);                         \
    DSR8O(b[2], bV0, 4096);    DSR8O(b[3], bV0, 6144);                         \
    DSR8O(a[0][1], aV1, 0);    DSR8O(a[1][1], aV1, 2048);                      \
    DSR8O(a[2][1], aV1, 4096); DSR8O(a[3][1], aV1, 6144);                      \
    STAGE_B(s_ + 1, 0, BW_); STAGE_B(s_ + 1, 1, BW_);                          \
    STAGE_A(s_ + 2, 0, AW_); STAGE_A(s_ + 2, 1, AW_);                          \
    LGK(7); P1; CL4(0, 0, 0); PIN; P0; DSR8O(b[0], bV0, 8192);                 \
    LGK(7); P1; CL4(1, 1, 0); PIN; P0; DSR8O(b[1], bV0, 10240);                \
    LGK(7); P1; CL4(2, 2, 0); PIN; P0; DSR8O(b[2], bV0, 12288);                \
    LGK(7); P1; CL4(3, 3, 0); PIN; P0; DSR8O(b[3], bV0, 14336);                \
    LGK(3); P1; CL4(4, 0, 0); PIN; P0; DSR8O(b[0], bV1, 0);                    \
    LGK(3); P1; CL4(5, 1, 0); PIN; P0; DSR8O(b[1], bV1, 2048);                 \
    LGK(3); P1; CL4(6, 2, 0); PIN; P0; DSR8O(b[2], bV1, 4096);                 \
    LGK(3); P1; CL4(7, 3, 0); PIN; P0; DSR8O(b[3], bV1, 6144);                 \
    LGK(3); P1; CL4(0, 0, 1); PIN; P0; DSR8O(b[0], bV1, 8192);                 \
    LGK(3); P1; CL4(1, 1, 1); PIN; P0; DSR8O(b[1], bV1, 10240);                \
    LGK(3); P1; CL4(2, 2, 1); PIN; P0; DSR8O(b[2], bV1, 12288);                \
    LGK(3); P1; CL4(3, 3, 1); PIN; P0; DSR8O(b[3], bV1, 14336);                \
    LGK(3); P1; CL4(4, 0, 1); PIN; P0;                                         \
    LGK(2); P1; CL4(5, 1, 1); PIN; P0;                                         \
    LGK(1); P1; CL4(6, 2, 1); PIN; P0;                                         \
    LGK(0); P1; CL4(7, 3, 1); PIN; P0;                                         \
    if ((TM_) == 0) asm volatile("s_waitcnt vmcnt(4)" ::: "memory");           \
    __builtin_amdgcn_s_barrier();                                              \
} while (0)

__global__ __launch_bounds__(512, 2) void argmin_mfma(
    const ushort* __restrict__ zh, const ushort* __restrict__ eh,
    const float* __restrict__ enorm, unsigned long long* __restrict__ best)
{
    // ushort-indexed: A bufs x3 @ 0 / 16384 / 32768 (each 256 rows x 64),
    // B bufs x2 @ 49152 / 65536.  Total 81920 ushorts = 160 KiB exactly.
    __shared__ __align__(16) ushort lds[81920];

    const int t = threadIdx.x;
    const int w = t >> 6, lane = t & 63;
    const int quad = lane >> 4, l15 = lane & 15;

    // XCD-pairing swizzle (bijective, 256 blocks): each XCD's 32 resident
    // blocks share one 2MB B-panel in its L2.
    const int d = blockIdx.x;
    const int xcd = d & 7, slot = d >> 3;
    const int ns = xcd >> 1;
    const int mt = slot * 2 + (xcd & 1);
    const int m0 = mt * 256;
    const int nsN = ns * (NTPB * BN);         // 2048 * ns

    const int wrow = (w & 3) * 64;            // wave row base in A tile
    const int wcol = (w >> 2) * 128;          // wave col base in B tile

    // staging lane geometry (pre-swizzled global source, linear LDS dest)
    const int l8 = lane >> 3, c8 = lane & 7;
    const int chunk = c8 ^ l8;
    const int soff = (w * 8 + l8) * DIMS + chunk * 8;
    const ushort* zA = zh + (size_t)m0 * DIMS;
    const float* enormg = enorm + nsN;

    // frag-read physical chunk offsets (ushorts): (kk*4+quad)^(l15&7) * 8
    const int pxo0 = (quad ^ (l15 & 7)) * 8;
    const int pxo1 = ((4 + quad) ^ (l15 & 7)) * 8;
    const int aro = (wrow + l15) * 64;
    const int bro = (wcol + l15) * 64;
    const unsigned ldsb = (unsigned)(size_t)AS3(&lds[0]);

    floatx4 acc[4][8];
    #pragma unroll
    for (int mi = 0; mi < 4; mi++)
        #pragma unroll
        for (int nj = 0; nj < 8; nj++)
            acc[mi][nj] = (floatx4){0.f, 0.f, 0.f, 0.f};

    float bs[16];
    int   bn_[16];
    #pragma unroll
    for (int k = 0; k < 16; k++) { bs[k] = 3.4e38f; bn_[k] = 0; }

    // prologue: A(0)->buf0, B(0)->B0, A(1)->buf1; vmcnt(4) -> A(0)/B(0)
    // landed, A(1) rides; barrier
    STAGE_A(0, 0, 0u);     STAGE_A(0, 1, 0u);
    STAGE_B(0, 0, 49152u); STAGE_B(0, 1, 49152u);
    STAGE_A(1, 0, 16384u); STAGE_A(1, 1, 16384u);
    asm volatile("s_waitcnt vmcnt(4)" ::: "memory");
    __builtin_amdgcn_s_barrier();

    // A-buffer base rotation: step s reads aR (= buf s%3), stages A(s+2)
    // into aW (= buf (s+2)%3); rotate (aR,aN,aW) <- (aN,aW,aR) each step.
    unsigned aR = 0u, aN = 16384u, aW = 32768u;

    for (int sp = 0; sp < NSTEPS; sp += 2) {
        STEP(sp, aR, 49152u, aW, 65536u, 0);
        { unsigned t_ = aR; aR = aN; aN = aW; aW = t_; }
        STEP(sp + 1, aR, 65536u, aW, 49152u, (sp == NSTEPS - 2) ? 2 : 0);
        { unsigned t_ = aR; aR = aN; aN = aW; aW = t_; }

        if ((sp & 7) == 6) {
            // n-tile finished: fold scores into running best, reset acc.
            // C/D frag: col = l15 (n), row = quad*4 + r (m).
            // enorm via global (L2-hot); vmcnt(0) also retires staging loads
            // that are ~2000cy old by now -> drain cost ~= enorm L2 latency.
            const int nt = sp >> 3;
            const int eb = nt * 256 + wcol + l15;
            const int nbase = nsN + eb;
            float en[8];
            #pragma unroll
            for (int nj = 0; nj < 8; nj++) {
                const float* ep_ = enormg + eb + nj * 16;
                asm volatile("global_load_dword %0, %1, off"
                             : "=v"(en[nj]) : "v"(ep_));
            }
            asm volatile("s_waitcnt vmcnt(0)" ::: "memory");
            __builtin_amdgcn_sched_barrier(0);
            #pragma unroll
            for (int nj = 0; nj < 8; nj++) {          // nj asc = n asc
                const int n = nbase + nj * 16;
                #pragma unroll
                for (int mi = 0; mi < 4; mi++) {
                    #pragma unroll
                    for (int r = 0; r < 4; r++) {
                        const int k = mi * 4 + r;
                        const float sc = fmaf(-2.0f, acc[mi][nj][r], en[nj]);
                        if (sc < bs[k]) { bs[k] = sc; bn_[k] = n; }
                    }
                    acc[mi][nj] = (floatx4){0.f, 0.f, 0.f, 0.f};
                }
            }
        }
    }

    // drain tail staging gloads before epilogue/endpgm (once, cheap)
    asm volatile("s_waitcnt vmcnt(0)" ::: "memory");

    // once per block: pack, shfl-min over l15 group, atomicMin across splits
    #pragma unroll
    for (int mi = 0; mi < 4; mi++)
        #pragma unroll
        for (int r = 0; r < 4; r++) {
            const int k = mi * 4 + r;
            unsigned su = __builtin_bit_cast(unsigned, bs[k]);
            su = (su & 0x80000000u) ? ~su : (su | 0x80000000u);  // order-preserving
            unsigned long long key = ((unsigned long long)su << 32) | (unsigned)bn_[k];
            #pragma unroll
            for (int off = 1; off < 16; off <<= 1) {
                unsigned long long o = __shfl_xor(key, off, 64);
                key = (o < key) ? o : key;
            }
            if (l15 == 0) atomicMin(&best[m0 + wrow + mi * 16 + quad * 4 + r], key);
        }
}

// one block per 32 rows: idx from packed keys, gather z_q, loss + idx stats;
// last block to finish runs the finalize.
__global__ __launch_bounds__(256) void gather_loss_kernel(
    const float* __restrict__ z, const float* __restrict__ emb,
    const unsigned long long* __restrict__ best,
    float* __restrict__ out, double* __restrict__ sums, unsigned* __restrict__ counter)
{
    __shared__ int sIdx[32];
    __shared__ double red[4];
    const int t = threadIdx.x;
    const int row0 = blockIdx.x * 32;
    double myIdxSum = 0.0, myIdxSq = 0.0;
    if (t < 32) {
        int row = row0 + t;
        int idx = (int)(unsigned)(best[row] & 0xFFFFFFFFULL);
        sIdx[t] = idx;
        out[IDX_OFF + row] = (float)idx;
        myIdxSum = (double)idx;
        myIdxSq = (double)idx * (double)idx;
    }
    __syncthreads();
    double acc = 0.0;
    #pragma unroll 4
    for (int i = 0; i < 16; i++) {
        int e = i * 1024 + t * 4;        // 32 rows x 512 = 16384 elems per block
        int rl = e >> 9;
        int c = e & 511;
        int idx = sIdx[rl];
        float4 zv = *(const float4*)(z + (size_t)(row0 + rl) * DIMS + c);
        float4 ev = *(const float4*)(emb + (size_t)idx * DIMS + c);
        *(float4*)(out + (size_t)(row0 + rl) * DIMS + c) = ev;  // z_q_st value == z_q
        float dx = zv.x - ev.x, dy = zv.y - ev.y;
        float dz = zv.z - ev.z, dw = zv.w - ev.w;
        acc += (double)(dx * dx + dy * dy) + (double)(dz * dz + dw * dw);
    }
    const int lane = t & 63, wv = t >> 6;
    #pragma unroll
    for (int off = 32; off > 0; off >>= 1) {
        acc      += __shfl_down(acc, off, 64);
        myIdxSum += __shfl_down(myIdxSum, off, 64);
        myIdxSq  += __shfl_down(myIdxSq, off, 64);
    }
    if (lane == 0) red[wv] = acc;
    __syncthreads();
    if (t == 0) {
        double tot = red[0] + red[1] + red[2] + red[3];
        atomicAdd(&sums[0], tot);
        atomicAdd(&sums[1], myIdxSum);   // wave 0 held all idx stats
        atomicAdd(&sums[2], myIdxSq);
        __threadfence();
        unsigned old = atomicAdd(counter, 1u);
        if (old == gridDim.x - 1) {
            __threadfence();
            double s0 = atomicAdd(&sums[0], 0.0);
            double s1 = atomicAdd(&sums[1], 0.0);
            double s2 = atomicAdd(&sums[2], 0.0);
            out[LOSS_OFF] = (float)(1.25 * s0 / (double)((size_t)BT * DIMS));
            double m = s1 / (double)BT;
            out[V_OFF] = (float)(s2 / (double)BT - m * m);
        }
    }
}

extern "C" void kernel_launch(void* const* d_in, const int* in_sizes, int n_in,
                              void* d_out, int out_size, void* d_ws, size_t ws_size,
                              hipStream_t stream) {
    const float* z = (const float*)d_in[0];
    const float* emb = (const float*)d_in[1];
    float* out = (float*)d_out;
    char* ws = (char*)d_ws;
    unsigned long long* best = (unsigned long long*)(ws + BEST_OFF);
    float* enorm  = (float*)(ws + ENORM_OFF);
    double* sums  = (double*)(ws + SUMS_OFF);
    unsigned* counter = (unsigned*)(ws + CNT_OFF);

    // bf16 scratch in the z_q region of out (fully overwritten by gather at the end)
    ushort* zh = (ushort*)out;
    ushort* ehh = zh + (size_t)BT * DIMS;

    hipLaunchKernelGGL(prep_kernel, dim3(NE / 4 + BT / 4), dim3(256), 0, stream,
                       z, emb, zh, ehh, enorm, best, sums, counter);
    hipLaunchKernelGGL(argmin_mfma, dim3(256), dim3(512), 0, stream,
                       zh, ehh, enorm, best);
    hipLaunchKernelGGL(gather_loss_kernel, dim3(BT / 32), dim3(256), 0, stream,
                       z, emb, best, out, sums, counter);
}